// Round 3
// baseline (1311.636 us; speedup 1.0000x reference)
//
#include <hip/hip_runtime.h>
#include <stdint.h>
#include <stddef.h>

// Problem constants
#define BATCH 4
#define SEQ   2048
#define EDIM  2048
#define NH    16
#define HD    128
#define MTOT  (BATCH*SEQ)   // 8192

// softmax scale folded into Q at GEMM1 epilogue: 1/sqrt(128) * log2(e)
#define QSCALE (0.08838834764831845f * 1.4426950408889634f)

typedef __bf16 bf16_t;
typedef __attribute__((ext_vector_type(8))) __bf16 bf16x8;
typedef __attribute__((ext_vector_type(4))) __bf16 bf16x4;
typedef __attribute__((ext_vector_type(4))) float f32x4;

// async global->LDS, 16B per lane. LDS dest must be wave-uniform-base + lane*16.
#define GLD16(l, g) __builtin_amdgcn_global_load_lds( \
    (const uint32_t __attribute__((address_space(1)))*)(g), \
    (uint32_t __attribute__((address_space(3)))*)(l), 16, 0, 0)

#define RAW_BARRIER()  asm volatile("s_barrier" ::: "memory")
#define WAITCNT_VM(n)  asm volatile("s_waitcnt vmcnt(" #n ")" ::: "memory")

// ---------------------------------------------------------------------------
// fp32 -> bf16 cast, 4 elements/thread
// ---------------------------------------------------------------------------
__global__ void cast_bf16_kernel(const float* __restrict__ in,
                                 bf16_t* __restrict__ out, int n4) {
    int i = blockIdx.x * blockDim.x + threadIdx.x;
    if (i < n4) {
        float4 v = ((const float4*)in)[i];
        bf16x4 o = { (__bf16)v.x, (__bf16)v.y, (__bf16)v.z, (__bf16)v.w };
        ((bf16x4*)out)[i] = o;
    }
}

// ---------------------------------------------------------------------------
// NT GEMM: C[m][n] = sum_k A[m][k] * B[n][k]   (A:[M,K], B:[N,K], row-major)
// 128x128 tile, BK=64, 256 threads (4 waves, 2x2 of 64x64), 16x16x32 bf16 MFMA.
// LDS XOR-swizzle: slot(row, c8) holds G[row][c8 ^ (row&7)] (8-el chunks).
// EPI=0: route to q/k/v buffers (q,k: [bh][s][d] bf16, Q pre-scaled by QSCALE;
//        v transposed [bh][d][s])
// EPI=1: fp32 out + bias
// ---------------------------------------------------------------------------
template<int EPI>
__global__ __launch_bounds__(256)
void gemm_nt(const bf16_t* __restrict__ A, const bf16_t* __restrict__ B,
             int M, int N, int K,
             float* __restrict__ outf, const float* __restrict__ bias,
             bf16_t* __restrict__ qb, bf16_t* __restrict__ kb,
             bf16_t* __restrict__ vb)
{
    __shared__ bf16_t As[128*64];
    __shared__ bf16_t Bs[128*64];
    const int tid  = threadIdx.x;
    const int lane = tid & 63;
    const int l15  = lane & 15;
    const int quad = lane >> 4;
    const int wave = tid >> 6;
    const int wm = (wave & 1) * 64;
    const int wn = (wave >> 1) * 64;
    const int bm = blockIdx.x * 128;
    const int bn = blockIdx.y * 128;

    f32x4 acc[4][4] = {};

    for (int k0 = 0; k0 < K; k0 += 64) {
#pragma unroll
        for (int i = 0; i < 4; i++) {
            int lin = i*2048 + tid*8;
            int row = lin >> 6;          // 0..127
            int c   = (lin >> 3) & 7;    // 8-el chunk in row
            int scol = (c ^ (row & 7)) * 8;
            GLD16(&As[lin], A + (long)(bm + row)*K + k0 + scol);
            GLD16(&Bs[lin], B + (long)(bn + row)*K + k0 + scol);
        }
        __syncthreads();
#pragma unroll
        for (int kk = 0; kk < 2; kk++) {
            bf16x8 af[4], bfr[4];
#pragma unroll
            for (int mt = 0; mt < 4; mt++)
                af[mt] = *(const bf16x8*)&As[(wm + mt*16 + l15)*64 +
                                             (((kk*4 + quad) ^ (l15 & 7)) * 8)];
#pragma unroll
            for (int nt = 0; nt < 4; nt++)
                bfr[nt] = *(const bf16x8*)&Bs[(wn + nt*16 + l15)*64 +
                                              (((kk*4 + quad) ^ (l15 & 7)) * 8)];
#pragma unroll
            for (int mt = 0; mt < 4; mt++)
#pragma unroll
                for (int nt = 0; nt < 4; nt++)
                    acc[mt][nt] = __builtin_amdgcn_mfma_f32_16x16x32_bf16(
                        af[mt], bfr[nt], acc[mt][nt], 0, 0, 0);
        }
        __syncthreads();
    }

    if (EPI == 0) {
        // qkv routing epilogue. which/h are block-uniform (128-col tile
        // never straddles a 2048 or 128 boundary).
#pragma unroll
        for (int nt = 0; nt < 4; nt++) {
            int colg = bn + wn + nt*16 + l15;
            int which = colg >> 11;
            int e = colg & 2047;
            int h = e >> 7, d = e & 127;
#pragma unroll
            for (int mt = 0; mt < 4; mt++) {
#pragma unroll
                for (int r = 0; r < 4; r++) {
                    int rowg = bm + wm + mt*16 + quad*4 + r;
                    int b = rowg >> 11, s = rowg & 2047;
                    long bh = (long)b*NH + h;
                    if (which == 0)
                        qb[(bh*SEQ + s)*HD + d] = (__bf16)(acc[mt][nt][r] * QSCALE);
                    else if (which == 1)
                        kb[(bh*SEQ + s)*HD + d] = (__bf16)acc[mt][nt][r];
                    else
                        vb[(bh*HD + d)*SEQ + s] = (__bf16)acc[mt][nt][r];
                }
            }
        }
    } else {
#pragma unroll
        for (int nt = 0; nt < 4; nt++) {
            int colg = bn + wn + nt*16 + l15;
            float bv = bias[colg];
#pragma unroll
            for (int mt = 0; mt < 4; mt++)
#pragma unroll
                for (int r = 0; r < 4; r++) {
                    int rowg = bm + wm + mt*16 + quad*4 + r;
                    outf[(long)rowg*EDIM + colg] = acc[mt][nt][r] + bv;
                }
        }
    }
}

// ---------------------------------------------------------------------------
// Flash attention v3: one block = 128 q rows of one (b,h); 4 waves x 32 rows.
// KV-tile = 64. LDS 48 KB -> 3 blocks/CU (was 64 KB / 2):
//   K0|K1 double-buffered [64 s][128 d] (16 KB each), single V [128 d][64 s].
// Pipeline (per iter, raw s_barrier + manual vmcnt, FIFO per-thread = 8 ops/iter):
//   B1 -> issue V(t) then K(t+1) -> vm(8) [K(t) mine landed] -> B2 [all landed]
//   -> QK(t) -> vm(4) [V(t) mine landed] -> B3 [all Kc reads done + V landed]
//   -> softmax + P write into Kc (wave-private) -> PV(t) reading V + P.
// Row sums via MFMA with all-ones B-fragment (l = extra O column; no sum
// shuffles, no l_i bookkeeping). Rescale of O/sum guarded by __any(max moved).
// Q arrives pre-scaled by QSCALE, so softmax is exp2(sc - m).
// ---------------------------------------------------------------------------
__global__ __launch_bounds__(256, 3)
void attn_kernel(const bf16_t* __restrict__ qb, const bf16_t* __restrict__ kb,
                 const bf16_t* __restrict__ vb, bf16_t* __restrict__ ob)
{
    __shared__ bf16_t SM[24576];        // 48 KB
    bf16_t* const K0 = SM;              // 8192 el = 16 KB
    bf16_t* const K1 = SM + 8192;
    bf16_t* const Vb = SM + 16384;      // 8192 el, [128 d][64 s]

    const int tid  = threadIdx.x;
    const int lane = tid & 63;
    const int l15  = lane & 15;
    const int quad = lane >> 4;
    const int wave = tid >> 6;

    // XCD-aware swizzle: xcd = blockIdx%8 fixed for all 16 q-tiles of a head.
    const int l    = blockIdx.x;
    const int slot = l >> 3;
    const int bh   = (l & 7) + 8 * (slot >> 4);   // 0..63
    const int q0   = (slot & 15) * 128;
    const int b    = bh >> 4;
    const int h    = bh & 15;

    const bf16_t* qg  = qb + ((long)bh*SEQ + q0)*HD;
    const bf16_t* kg0 = kb + (long)bh*SEQ*HD;
    const bf16_t* vg0 = vb + (long)bh*HD*SEQ;

    // ---- prologue: stage Q tile (32 KB) into K0|K1 region, read fragments --
#pragma unroll
    for (int i = 0; i < 8; i++) {
        int lin = i*2048 + tid*8;
        int row = lin >> 7;              // 0..127
        int c   = (lin >> 3) & 15;       // 16 chunks per 128-el row
        GLD16(&SM[lin], qg + (long)row*HD + ((c ^ (row & 15)) * 8));
    }
    WAITCNT_VM(0);
    __syncthreads();
    bf16x8 qf[2][4];
#pragma unroll
    for (int qt = 0; qt < 2; qt++)
#pragma unroll
        for (int ks = 0; ks < 4; ks++)
            qf[qt][ks] = *(const bf16x8*)&SM[(wave*32 + qt*16 + l15)*128 +
                                             (((ks*4 + quad) ^ l15) * 8)];
    __syncthreads();                     // all Q reads done before K0 overwrite

    // ---- issue tile-0 K loads (V(0) issued inside iter 0) ----
#pragma unroll
    for (int i = 0; i < 4; i++) {
        int lin = i*2048 + tid*8;
        int row = lin >> 7, c = (lin >> 3) & 15;
        GLD16(&K0[lin], kg0 + (long)row*HD + ((c ^ (row & 15)) * 8));
    }

    f32x4 oacc[2][8] = {};
    f32x4 sacc[2] = {};                  // row sums (every col identical)
    float m_i[2][4];
#pragma unroll
    for (int qt = 0; qt < 2; qt++)
#pragma unroll
        for (int r = 0; r < 4; r++) m_i[qt][r] = -1e30f;

    const bf16x8 onesf = { (__bf16)1.f,(__bf16)1.f,(__bf16)1.f,(__bf16)1.f,
                           (__bf16)1.f,(__bf16)1.f,(__bf16)1.f,(__bf16)1.f };

    const int NT = SEQ / 64;             // 32
    for (int t = 0; t < NT; t++) {
        bf16_t* const Kc = (t & 1) ? K1 : K0;
        bf16_t* const Kn = (t & 1) ? K0 : K1;

        RAW_BARRIER();                   // B1: all waves done PV(t-1) & P(t-1) reads
        {   // V(t) first, then K(t+1)  (FIFO order matters for the vmcnts)
            const bf16_t* vg = vg0 + t*64;
            int tn = (t + 1 == NT) ? 0 : t + 1;
            const bf16_t* kg = kg0 + (long)tn*64*HD;
#pragma unroll
            for (int i = 0; i < 4; i++) {
                int lin = i*2048 + tid*8;
                int row = lin >> 6, c = (lin >> 3) & 7;
                GLD16(&Vb[lin], vg + (long)row*SEQ + ((c ^ (row & 7)) * 8));
            }
#pragma unroll
            for (int i = 0; i < 4; i++) {
                int lin = i*2048 + tid*8;
                int row = lin >> 7, c = (lin >> 3) & 15;
                GLD16(&Kn[lin], kg + (long)row*HD + ((c ^ (row & 15)) * 8));
            }
        }
        WAITCNT_VM(8);                   // my K(t) landed ([V(t),K(t+1)] in flight)
        RAW_BARRIER();                   // B2: everyone's K(t) in LDS

        // ---- S = Q K^T  (sc[qt][st], kv rows: st*16+l15) ----
        f32x4 sc[2][4] = {};
#pragma unroll
        for (int ks = 0; ks < 4; ks++) {
            bf16x8 kf[4];
#pragma unroll
            for (int st = 0; st < 4; st++)
                kf[st] = *(const bf16x8*)&Kc[(st*16 + l15)*128 +
                                             (((ks*4 + quad) ^ l15) * 8)];
#pragma unroll
            for (int qt = 0; qt < 2; qt++)
#pragma unroll
                for (int st = 0; st < 4; st++)
                    sc[qt][st] = __builtin_amdgcn_mfma_f32_16x16x32_bf16(
                        qf[qt][ks], kf[st], sc[qt][st], 0, 0, 0);
        }

        WAITCNT_VM(4);                   // my V(t) landed (K(t+1) stays in flight)
        RAW_BARRIER();                   // B3: all QK reads of Kc done + all V landed

        // ---- phase 1: row maxima (8 independent shuffle chains) ----
        f32x4 av[2];
        bool anych = false;
#pragma unroll
        for (int qt = 0; qt < 2; qt++) {
#pragma unroll
            for (int r = 0; r < 4; r++) {
                float mx = fmaxf(fmaxf(sc[qt][0][r], sc[qt][1][r]),
                                 fmaxf(sc[qt][2][r], sc[qt][3][r]));
#pragma unroll
                for (int dlt = 1; dlt < 16; dlt <<= 1)
                    mx = fmaxf(mx, __shfl_xor(mx, dlt, 64));
                float mo = m_i[qt][r];
                float mnew = fmaxf(mo, mx);
                m_i[qt][r] = mnew;
                av[qt][r] = exp2f(mo - mnew);
                anych |= (mnew > mo);
            }
        }
        // ---- guarded rescale (skipped once maxima stabilize) ----
        if (__any(anych)) {
#pragma unroll
            for (int qt = 0; qt < 2; qt++) {
                sacc[qt] *= av[qt];
#pragma unroll
                for (int dt = 0; dt < 8; dt++) oacc[qt][dt] *= av[qt];
            }
        }

        // ---- phase 2: exp + P write into Kc (wave-private slice) ----
        bf16_t* const Pp = Kc + wave*2048;   // [32 q][64 kv] swizzled
#pragma unroll
        for (int qt = 0; qt < 2; qt++) {
#pragma unroll
            for (int r = 0; r < 4; r++) {
                float mnew = m_i[qt][r];
                int prow = qt*16 + quad*4 + r;
#pragma unroll
                for (int st = 0; st < 4; st++) {
                    float p = exp2f(sc[qt][st][r] - mnew);
                    int cg = st*2 + (l15 >> 3);
                    Pp[prow*64 + ((cg ^ (prow & 7)) * 8) + (l15 & 7)] = (__bf16)p;
                }
            }
        }
        // P wave-private: same-wave LDS RAW covered by compiler lgkmcnt.

        // ---- PV accumulate + MFMA row-sum (ones B-fragment) ----
        bf16x8 pf[2][2];
#pragma unroll
        for (int qt = 0; qt < 2; qt++)
#pragma unroll
            for (int kt = 0; kt < 2; kt++)
                pf[qt][kt] = *(const bf16x8*)&Pp[(qt*16 + l15)*64 +
                                                 (((kt*4 + quad) ^ (l15 & 7)) * 8)];
#pragma unroll
        for (int kt = 0; kt < 2; kt++) {
#pragma unroll
            for (int qt = 0; qt < 2; qt++)
                sacc[qt] = __builtin_amdgcn_mfma_f32_16x16x32_bf16(
                    pf[qt][kt], onesf, sacc[qt], 0, 0, 0);
#pragma unroll
            for (int dt = 0; dt < 8; dt++) {
                bf16x8 vf = *(const bf16x8*)&Vb[(dt*16 + l15)*64 +
                                                (((kt*4 + quad) ^ (l15 & 7)) * 8)];
#pragma unroll
                for (int qt = 0; qt < 2; qt++)
                    oacc[qt][dt] = __builtin_amdgcn_mfma_f32_16x16x32_bf16(
                        pf[qt][kt], vf, oacc[qt][dt], 0, 0, 0);
            }
        }
    }

    // ---- epilogue: O / l, write [b][s][h*128+d] bf16 ----
#pragma unroll
    for (int qt = 0; qt < 2; qt++) {
        float inv[4];
#pragma unroll
        for (int r = 0; r < 4; r++) inv[r] = 1.0f / sacc[qt][r];
#pragma unroll
        for (int dt = 0; dt < 8; dt++)
#pragma unroll
            for (int r = 0; r < 4; r++) {
                int s = q0 + wave*32 + qt*16 + quad*4 + r;
                int d = dt*16 + l15;
                ob[((long)b*SEQ + s)*EDIM + h*HD + d] =
                    (__bf16)(oacc[qt][dt][r] * inv[r]);
            }
    }
}

// ---------------------------------------------------------------------------
extern "C" void kernel_launch(void* const* d_in, const int* in_sizes, int n_in,
                              void* d_out, int out_size, void* d_ws, size_t ws_size,
                              hipStream_t stream) {
    const float* x    = (const float*)d_in[0];
    const float* wqkv = (const float*)d_in[1];
    const float* wout = (const float*)d_in[2];
    const float* bout = (const float*)d_in[3];
    float* out = (float*)d_out;

    char* w = (char*)d_ws;
    bf16_t* xb    = (bf16_t*)w; w += (size_t)MTOT*EDIM*2;     // 33.5 MB
    bf16_t* wqkvb = (bf16_t*)w; w += (size_t)3*EDIM*EDIM*2;   // 25.2 MB
    bf16_t* woutb = (bf16_t*)w; w += (size_t)EDIM*EDIM*2;     //  8.4 MB
    bf16_t* qbuf  = (bf16_t*)w; w += (size_t)MTOT*EDIM*2;     // 33.5 MB  [bh][s][d]
    bf16_t* kbuf  = (bf16_t*)w; w += (size_t)MTOT*EDIM*2;     // 33.5 MB  [bh][s][d]
    bf16_t* vbuf  = (bf16_t*)w; w += (size_t)MTOT*EDIM*2;     // 33.5 MB  [bh][d][s]
    bf16_t* attnb = (bf16_t*)w; w += (size_t)MTOT*EDIM*2;     // 33.5 MB  [b][s][e]

    cast_bf16_kernel<<<MTOT*EDIM/1024, 256, 0, stream>>>(x, xb, MTOT*EDIM/4);
    cast_bf16_kernel<<<3*EDIM*EDIM/1024, 256, 0, stream>>>(wqkv, wqkvb, 3*EDIM*EDIM/4);
    cast_bf16_kernel<<<EDIM*EDIM/1024, 256, 0, stream>>>(wout, woutb, EDIM*EDIM/4);

    gemm_nt<0><<<dim3(MTOT/128, 3*EDIM/128), 256, 0, stream>>>(
        xb, wqkvb, MTOT, 3*EDIM, EDIM, nullptr, nullptr, qbuf, kbuf, vbuf);

    attn_kernel<<<dim3(SEQ/128 * BATCH*NH), 256, 0, stream>>>(qbuf, kbuf, vbuf, attnb);

    gemm_nt<1><<<dim3(MTOT/128, EDIM/128), 256, 0, stream>>>(
        attnb, woutb, MTOT, EDIM, EDIM, out, bout, nullptr, nullptr, nullptr);
}

// Round 4
// 762.332 us; speedup vs baseline: 1.7206x; 1.7206x over previous
//
#include <hip/hip_runtime.h>
#include <stdint.h>
#include <stddef.h>

// Problem constants
#define BATCH 4
#define SEQ   2048
#define EDIM  2048
#define NH    16
#define HD    128
#define MTOT  (BATCH*SEQ)   // 8192

// softmax scale folded into Q at GEMM1 epilogue: 1/sqrt(128) * log2(e)
#define QSCALE (0.08838834764831845f * 1.4426950408889634f)

typedef __bf16 bf16_t;
typedef __attribute__((ext_vector_type(8))) __bf16 bf16x8;
typedef __attribute__((ext_vector_type(4))) __bf16 bf16x4;
typedef __attribute__((ext_vector_type(4))) float f32x4;

// async global->LDS, 16B per lane. LDS dest must be wave-uniform-base + lane*16.
#define GLD16(l, g) __builtin_amdgcn_global_load_lds( \
    (const uint32_t __attribute__((address_space(1)))*)(g), \
    (uint32_t __attribute__((address_space(3)))*)(l), 16, 0, 0)

#define RAW_BARRIER()  asm volatile("s_barrier" ::: "memory")
#define WAITCNT_VM(n)  asm volatile("s_waitcnt vmcnt(" #n ")" ::: "memory")

// ---------------------------------------------------------------------------
// fp32 -> bf16 cast, 4 elements/thread
// ---------------------------------------------------------------------------
__global__ void cast_bf16_kernel(const float* __restrict__ in,
                                 bf16_t* __restrict__ out, int n4) {
    int i = blockIdx.x * blockDim.x + threadIdx.x;
    if (i < n4) {
        float4 v = ((const float4*)in)[i];
        bf16x4 o = { (__bf16)v.x, (__bf16)v.y, (__bf16)v.z, (__bf16)v.w };
        ((bf16x4*)out)[i] = o;
    }
}

// ---------------------------------------------------------------------------
// NT GEMM: C[m][n] = sum_k A[m][k] * B[n][k]   (A:[M,K], B:[N,K], row-major)
// 128x128 tile, BK=64, 256 threads (4 waves, 2x2 of 64x64), 16x16x32 bf16 MFMA.
// LDS XOR-swizzle: slot(row, c8) holds G[row][c8 ^ (row&7)] (8-el chunks).
// EPI=0: route to q/k/v buffers (q,k: [bh][s][d] bf16, Q pre-scaled by QSCALE;
//        v transposed [bh][d][s])
// EPI=1: fp32 out + bias
// ---------------------------------------------------------------------------
template<int EPI>
__global__ __launch_bounds__(256)
void gemm_nt(const bf16_t* __restrict__ A, const bf16_t* __restrict__ B,
             int M, int N, int K,
             float* __restrict__ outf, const float* __restrict__ bias,
             bf16_t* __restrict__ qb, bf16_t* __restrict__ kb,
             bf16_t* __restrict__ vb)
{
    __shared__ bf16_t As[128*64];
    __shared__ bf16_t Bs[128*64];
    const int tid  = threadIdx.x;
    const int lane = tid & 63;
    const int l15  = lane & 15;
    const int quad = lane >> 4;
    const int wave = tid >> 6;
    const int wm = (wave & 1) * 64;
    const int wn = (wave >> 1) * 64;
    const int bm = blockIdx.x * 128;
    const int bn = blockIdx.y * 128;

    f32x4 acc[4][4] = {};

    for (int k0 = 0; k0 < K; k0 += 64) {
#pragma unroll
        for (int i = 0; i < 4; i++) {
            int lin = i*2048 + tid*8;
            int row = lin >> 6;          // 0..127
            int c   = (lin >> 3) & 7;    // 8-el chunk in row
            int scol = (c ^ (row & 7)) * 8;
            GLD16(&As[lin], A + (long)(bm + row)*K + k0 + scol);
            GLD16(&Bs[lin], B + (long)(bn + row)*K + k0 + scol);
        }
        __syncthreads();
#pragma unroll
        for (int kk = 0; kk < 2; kk++) {
            bf16x8 af[4], bfr[4];
#pragma unroll
            for (int mt = 0; mt < 4; mt++)
                af[mt] = *(const bf16x8*)&As[(wm + mt*16 + l15)*64 +
                                             (((kk*4 + quad) ^ (l15 & 7)) * 8)];
#pragma unroll
            for (int nt = 0; nt < 4; nt++)
                bfr[nt] = *(const bf16x8*)&Bs[(wn + nt*16 + l15)*64 +
                                              (((kk*4 + quad) ^ (l15 & 7)) * 8)];
#pragma unroll
            for (int mt = 0; mt < 4; mt++)
#pragma unroll
                for (int nt = 0; nt < 4; nt++)
                    acc[mt][nt] = __builtin_amdgcn_mfma_f32_16x16x32_bf16(
                        af[mt], bfr[nt], acc[mt][nt], 0, 0, 0);
        }
        __syncthreads();
    }

    if (EPI == 0) {
        // qkv routing epilogue. which/h are block-uniform (128-col tile
        // never straddles a 2048 or 128 boundary).
#pragma unroll
        for (int nt = 0; nt < 4; nt++) {
            int colg = bn + wn + nt*16 + l15;
            int which = colg >> 11;
            int e = colg & 2047;
            int h = e >> 7, d = e & 127;
#pragma unroll
            for (int mt = 0; mt < 4; mt++) {
#pragma unroll
                for (int r = 0; r < 4; r++) {
                    int rowg = bm + wm + mt*16 + quad*4 + r;
                    int b = rowg >> 11, s = rowg & 2047;
                    long bh = (long)b*NH + h;
                    if (which == 0)
                        qb[(bh*SEQ + s)*HD + d] = (__bf16)(acc[mt][nt][r] * QSCALE);
                    else if (which == 1)
                        kb[(bh*SEQ + s)*HD + d] = (__bf16)acc[mt][nt][r];
                    else
                        vb[(bh*HD + d)*SEQ + s] = (__bf16)acc[mt][nt][r];
                }
            }
        }
    } else {
#pragma unroll
        for (int nt = 0; nt < 4; nt++) {
            int colg = bn + wn + nt*16 + l15;
            float bv = bias[colg];
#pragma unroll
            for (int mt = 0; mt < 4; mt++)
#pragma unroll
                for (int r = 0; r < 4; r++) {
                    int rowg = bm + wm + mt*16 + quad*4 + r;
                    outf[(long)rowg*EDIM + colg] = acc[mt][nt][r] + bv;
                }
        }
    }
}

// ---------------------------------------------------------------------------
// Flash attention v4: round-2 memory shape + round-3 softmax.
// One block = 128 q rows of one (b,h); 4 waves x 32 rows. KV-tile = 64.
// LDS 64 KB (K0|K1|V0|V1, all double-buffered) -> 2 blocks/CU. This is
// DELIBERATE: 2 blocks/CU keeps ~4 active heads x 1 MB K/V per XCD = 4 MB
// = exactly XCD L2 size. 3 blocks/CU (round 3) thrashed L2: FETCH 52MB->1.1GB.
// Pipeline: B1 -> issue K(t+1),V(t+1) -> vm(8) [tile t mine landed] -> B2
// [all landed] -> QK(t) -> B3 [all Kc reads done] -> softmax + P into Kc
// (wave-private) -> PV(t).
// Row sums via MFMA ones-fragment; rescale guarded by __any(max moved);
// Q arrives pre-scaled so softmax is exp2(sc - m).
// ---------------------------------------------------------------------------
__global__ __launch_bounds__(256, 2)
void attn_kernel(const bf16_t* __restrict__ qb, const bf16_t* __restrict__ kb,
                 const bf16_t* __restrict__ vb, bf16_t* __restrict__ ob)
{
    __shared__ bf16_t SM[32768];        // 64 KB
    bf16_t* const K0 = SM;              // 8192 el = 16 KB each
    bf16_t* const K1 = SM + 8192;
    bf16_t* const V0 = SM + 16384;      // [128 d][64 s]
    bf16_t* const V1 = SM + 24576;

    const int tid  = threadIdx.x;
    const int lane = tid & 63;
    const int l15  = lane & 15;
    const int quad = lane >> 4;
    const int wave = tid >> 6;

    // XCD-aware swizzle: xcd = blockIdx%8 fixed for all 16 q-tiles of a head.
    const int l    = blockIdx.x;
    const int slot = l >> 3;
    const int bh   = (l & 7) + 8 * (slot >> 4);   // 0..63
    const int q0   = (slot & 15) * 128;
    const int b    = bh >> 4;
    const int h    = bh & 15;

    const bf16_t* qg  = qb + ((long)bh*SEQ + q0)*HD;
    const bf16_t* kg0 = kb + (long)bh*SEQ*HD;
    const bf16_t* vg0 = vb + (long)bh*HD*SEQ;

    // ---- prologue: stage Q tile (32 KB) into K0|K1 region, read fragments --
#pragma unroll
    for (int i = 0; i < 8; i++) {
        int lin = i*2048 + tid*8;
        int row = lin >> 7;              // 0..127
        int c   = (lin >> 3) & 15;       // 16 chunks per 128-el row
        GLD16(&SM[lin], qg + (long)row*HD + ((c ^ (row & 15)) * 8));
    }
    WAITCNT_VM(0);
    __syncthreads();
    bf16x8 qf[2][4];
#pragma unroll
    for (int qt = 0; qt < 2; qt++)
#pragma unroll
        for (int ks = 0; ks < 4; ks++)
            qf[qt][ks] = *(const bf16x8*)&SM[(wave*32 + qt*16 + l15)*128 +
                                             (((ks*4 + quad) ^ l15) * 8)];
    __syncthreads();                     // all Q reads done before K0 overwrite

    // ---- issue tile-0 K+V loads ----
#pragma unroll
    for (int i = 0; i < 4; i++) {
        int lin = i*2048 + tid*8;
        { int row = lin >> 7, c = (lin >> 3) & 15;
          GLD16(&K0[lin], kg0 + (long)row*HD + ((c ^ (row & 15)) * 8)); }
        { int row = lin >> 6, c = (lin >> 3) & 7;
          GLD16(&V0[lin], vg0 + (long)row*SEQ + ((c ^ (row & 7)) * 8)); }
    }

    f32x4 oacc[2][8] = {};
    f32x4 sacc[2] = {};                  // row sums (every col identical)
    float m_i[2][4];
#pragma unroll
    for (int qt = 0; qt < 2; qt++)
#pragma unroll
        for (int r = 0; r < 4; r++) m_i[qt][r] = -1e30f;

    const bf16x8 onesf = { (__bf16)1.f,(__bf16)1.f,(__bf16)1.f,(__bf16)1.f,
                           (__bf16)1.f,(__bf16)1.f,(__bf16)1.f,(__bf16)1.f };

    const int NT = SEQ / 64;             // 32
    for (int t = 0; t < NT; t++) {
        bf16_t* const Kc = (t & 1) ? K1 : K0;
        bf16_t* const Vc = (t & 1) ? V1 : V0;
        bf16_t* const Kn = (t & 1) ? K0 : K1;
        bf16_t* const Vn = (t & 1) ? V0 : V1;

        RAW_BARRIER();                   // B1: all waves done compute t-1
        {   // prefetch tile t+1 (wrap on last iter: harmless reload)
            int tn = (t + 1 == NT) ? 0 : t + 1;
            const bf16_t* kg = kg0 + (long)tn*64*HD;
            const bf16_t* vg = vg0 + tn*64;
#pragma unroll
            for (int i = 0; i < 4; i++) {
                int lin = i*2048 + tid*8;
                { int row = lin >> 7, c = (lin >> 3) & 15;
                  GLD16(&Kn[lin], kg + (long)row*HD + ((c ^ (row & 15)) * 8)); }
                { int row = lin >> 6, c = (lin >> 3) & 7;
                  GLD16(&Vn[lin], vg + (long)row*SEQ + ((c ^ (row & 7)) * 8)); }
            }
        }
        WAITCNT_VM(8);                   // my tile-t K+V landed (8 newer in flight)
        RAW_BARRIER();                   // B2: everyone's tile-t data in LDS

        // ---- S = Q K^T  (sc[qt][st], kv rows: st*16+l15) ----
        f32x4 sc[2][4] = {};
#pragma unroll
        for (int ks = 0; ks < 4; ks++) {
            bf16x8 kf[4];
#pragma unroll
            for (int st = 0; st < 4; st++)
                kf[st] = *(const bf16x8*)&Kc[(st*16 + l15)*128 +
                                             (((ks*4 + quad) ^ l15) * 8)];
#pragma unroll
            for (int qt = 0; qt < 2; qt++)
#pragma unroll
                for (int st = 0; st < 4; st++)
                    sc[qt][st] = __builtin_amdgcn_mfma_f32_16x16x32_bf16(
                        qf[qt][ks], kf[st], sc[qt][st], 0, 0, 0);
        }

        RAW_BARRIER();                   // B3: all QK reads of Kc done -> P-write safe

        // ---- phase 1: row maxima (8 independent shuffle chains) ----
        f32x4 av[2];
        bool anych = false;
#pragma unroll
        for (int qt = 0; qt < 2; qt++) {
#pragma unroll
            for (int r = 0; r < 4; r++) {
                float mx = fmaxf(fmaxf(sc[qt][0][r], sc[qt][1][r]),
                                 fmaxf(sc[qt][2][r], sc[qt][3][r]));
#pragma unroll
                for (int dlt = 1; dlt < 16; dlt <<= 1)
                    mx = fmaxf(mx, __shfl_xor(mx, dlt, 64));
                float mo = m_i[qt][r];
                float mnew = fmaxf(mo, mx);
                m_i[qt][r] = mnew;
                av[qt][r] = exp2f(mo - mnew);
                anych |= (mnew > mo);
            }
        }
        // ---- guarded rescale (skipped once maxima stabilize) ----
        if (__any(anych)) {
#pragma unroll
            for (int qt = 0; qt < 2; qt++) {
                sacc[qt] *= av[qt];
#pragma unroll
                for (int dt = 0; dt < 8; dt++) oacc[qt][dt] *= av[qt];
            }
        }

        // ---- phase 2: exp + P write into Kc (wave-private slice) ----
        bf16_t* const Pp = Kc + wave*2048;   // [32 q][64 kv] swizzled
#pragma unroll
        for (int qt = 0; qt < 2; qt++) {
#pragma unroll
            for (int r = 0; r < 4; r++) {
                float mnew = m_i[qt][r];
                int prow = qt*16 + quad*4 + r;
#pragma unroll
                for (int st = 0; st < 4; st++) {
                    float p = exp2f(sc[qt][st][r] - mnew);
                    int cg = st*2 + (l15 >> 3);
                    Pp[prow*64 + ((cg ^ (prow & 7)) * 8) + (l15 & 7)] = (__bf16)p;
                }
            }
        }
        // P wave-private: same-wave LDS RAW covered by compiler lgkmcnt.

        // ---- PV accumulate + MFMA row-sum (ones B-fragment) ----
        bf16x8 pf[2][2];
#pragma unroll
        for (int qt = 0; qt < 2; qt++)
#pragma unroll
            for (int kt = 0; kt < 2; kt++)
                pf[qt][kt] = *(const bf16x8*)&Pp[(qt*16 + l15)*64 +
                                                 (((kt*4 + quad) ^ (l15 & 7)) * 8)];
#pragma unroll
        for (int kt = 0; kt < 2; kt++) {
#pragma unroll
            for (int qt = 0; qt < 2; qt++)
                sacc[qt] = __builtin_amdgcn_mfma_f32_16x16x32_bf16(
                    pf[qt][kt], onesf, sacc[qt], 0, 0, 0);
#pragma unroll
            for (int dt = 0; dt < 8; dt++) {
                bf16x8 vf = *(const bf16x8*)&Vc[(dt*16 + l15)*64 +
                                                (((kt*4 + quad) ^ (l15 & 7)) * 8)];
#pragma unroll
                for (int qt = 0; qt < 2; qt++)
                    oacc[qt][dt] = __builtin_amdgcn_mfma_f32_16x16x32_bf16(
                        pf[qt][kt], vf, oacc[qt][dt], 0, 0, 0);
            }
        }
    }

    // ---- epilogue: O / l, write [b][s][h*128+d] bf16 ----
#pragma unroll
    for (int qt = 0; qt < 2; qt++) {
        float inv[4];
#pragma unroll
        for (int r = 0; r < 4; r++) inv[r] = 1.0f / sacc[qt][r];
#pragma unroll
        for (int dt = 0; dt < 8; dt++)
#pragma unroll
            for (int r = 0; r < 4; r++) {
                int s = q0 + wave*32 + qt*16 + quad*4 + r;
                int d = dt*16 + l15;
                ob[((long)b*SEQ + s)*EDIM + h*HD + d] =
                    (__bf16)(oacc[qt][dt][r] * inv[r]);
            }
    }
}

// ---------------------------------------------------------------------------
extern "C" void kernel_launch(void* const* d_in, const int* in_sizes, int n_in,
                              void* d_out, int out_size, void* d_ws, size_t ws_size,
                              hipStream_t stream) {
    const float* x    = (const float*)d_in[0];
    const float* wqkv = (const float*)d_in[1];
    const float* wout = (const float*)d_in[2];
    const float* bout = (const float*)d_in[3];
    float* out = (float*)d_out;

    char* w = (char*)d_ws;
    bf16_t* xb    = (bf16_t*)w; w += (size_t)MTOT*EDIM*2;     // 33.5 MB
    bf16_t* wqkvb = (bf16_t*)w; w += (size_t)3*EDIM*EDIM*2;   // 25.2 MB
    bf16_t* woutb = (bf16_t*)w; w += (size_t)EDIM*EDIM*2;     //  8.4 MB
    bf16_t* qbuf  = (bf16_t*)w; w += (size_t)MTOT*EDIM*2;     // 33.5 MB  [bh][s][d]
    bf16_t* kbuf  = (bf16_t*)w; w += (size_t)MTOT*EDIM*2;     // 33.5 MB  [bh][s][d]
    bf16_t* vbuf  = (bf16_t*)w; w += (size_t)MTOT*EDIM*2;     // 33.5 MB  [bh][d][s]
    bf16_t* attnb = (bf16_t*)w; w += (size_t)MTOT*EDIM*2;     // 33.5 MB  [b][s][e]

    cast_bf16_kernel<<<MTOT*EDIM/1024, 256, 0, stream>>>(x, xb, MTOT*EDIM/4);
    cast_bf16_kernel<<<3*EDIM*EDIM/1024, 256, 0, stream>>>(wqkv, wqkvb, 3*EDIM*EDIM/4);
    cast_bf16_kernel<<<EDIM*EDIM/1024, 256, 0, stream>>>(wout, woutb, EDIM*EDIM/4);

    gemm_nt<0><<<dim3(MTOT/128, 3*EDIM/128), 256, 0, stream>>>(
        xb, wqkvb, MTOT, 3*EDIM, EDIM, nullptr, nullptr, qbuf, kbuf, vbuf);

    attn_kernel<<<dim3(SEQ/128 * BATCH*NH), 256, 0, stream>>>(qbuf, kbuf, vbuf, attnb);

    gemm_nt<1><<<dim3(MTOT/128, EDIM/128), 256, 0, stream>>>(
        attnb, woutb, MTOT, EDIM, EDIM, out, bout, nullptr, nullptr, nullptr);
}